// Round 10
// baseline (110.804 us; speedup 1.0000x reference)
//
#include <hip/hip_runtime.h>
#include <hip/hip_bf16.h>

#define NL  128   // layers (n)
#define DK  256   // d_in (k)
#define DO_ 256   // d_out (o)
#define MB  1024  // batch (m)

typedef __attribute__((ext_vector_type(4))) float f32x4;
typedef __attribute__((ext_vector_type(8))) short bf16x8;
typedef __attribute__((ext_vector_type(8))) unsigned short u16x8;
typedef __attribute__((ext_vector_type(4))) unsigned short u16x4;

static __device__ __forceinline__ unsigned short f2bf(float f) {
  __hip_bfloat16 h = __float2bfloat16(f);
  return __builtin_bit_cast(unsigned short, h);
}

// ---------------------------------------------------------------------------
// Prep: W[n][k][o] fp32 -> Wt in MFMA B-fragment order, bf16 (verified R4-R9):
//   unit (o, kc[8-k chunk]) -> ob=o>>4, lrow=o&15, s=kc>>2, lhi=kc&3
//   elem offset = ((n*16+ob)*8 + s)*512 + (lhi*16+lrow)*8 + (k&7)
// so a wave's B-load for (ob, s) is ONE contiguous 1KB dwordx4 per lane.
// ---------------------------------------------------------------------------
__global__ __launch_bounds__(256) void wt_prep(const float* __restrict__ W,
                                               unsigned short* __restrict__ Wt) {
  const int n     = blockIdx.y;
  const int ktile = (blockIdx.x >> 2) * 64;
  const int otile = (blockIdx.x & 3) * 64;
  __shared__ float tile[64][65];  // +1 pad: conflict-free column reads
  const float* Wn = W + (size_t)n * DK * DO_;
  const int t  = threadIdx.x;
  const int lr = t >> 4;
  const int lc = (t & 15) * 4;
#pragma unroll
  for (int p = 0; p < 4; ++p) {
    const int k = p * 16 + lr;
    const float4 v = *(const float4*)(Wn + (size_t)(ktile + k) * DO_ + otile + lc);
    tile[k][lc + 0] = v.x; tile[k][lc + 1] = v.y;
    tile[k][lc + 2] = v.z; tile[k][lc + 3] = v.w;
  }
  __syncthreads();
  const int ol = t >> 2;            // local o 0..63
  const int o  = otile + ol;
  const int kq = t & 3;
  unsigned short* Wt_n = Wt + (size_t)n * DO_ * DK;
#pragma unroll
  for (int h = 0; h < 2; ++h) {
    u16x8 w;
#pragma unroll
    for (int j = 0; j < 8; ++j) w[j] = f2bf(tile[kq * 16 + h * 8 + j][ol]);
    const int kc = (ktile >> 3) + kq * 2 + h;   // global 8-k chunk id (0..31)
    const int ob = o >> 4, lrw = o & 15, s = kc >> 2, lh = kc & 3;
    *(u16x8*)(Wt_n + ((size_t)(ob * 8 + s) * 64 + lh * 16 + lrw) * 8) = w;
  }
}

// ---------------------------------------------------------------------------
// Main: GRANULARITY pivot. Block = 16 m-rows x 4 consecutive layers x 256 o.
// x read as 4KB-contiguous spans per m-row (8KB contiguous per wave-instr
// group) instead of 1KB-at-128KB-stride; out written 4KB-dense per row.
// Stage -> 32KB LDS (4 x verified swizzled [16][256] bf16 tiles), ONE barrier.
// Compute: wave = (layer j, o-half): M=16,N=128,K=256 -> 64 MFMA, 1-step
// static B-prefetch from L2-resident prefrag Wt. Bias in epilogue.
// XCD mapping: bid&7 -> n-group block [xcd*16,+16): 2MB Wt slice per XCD L2.
// ---------------------------------------------------------------------------
__global__ __launch_bounds__(512, 4) void nlinear_mfma(
    const float* __restrict__ X, const unsigned short* __restrict__ Wt,
    const float* __restrict__ bias, float* __restrict__ out) {
  const int bid  = blockIdx.x;
  const int ng   = (bid & 7) * 4 + ((bid >> 3) & 3);  // n-group 0..31 (4 n each)
  const int mt   = bid >> 5;                          // m-tile 0..63
  const int n0   = ng * 4;
  const int t    = threadIdx.x;
  const int wave = t >> 6;
  const int lane = t & 63;
  const int lrow = lane & 15;
  const int lhi  = lane >> 4;
  const int mbase = mt * 16;

  __shared__ unsigned short Alds[4][16][256];  // [layer][m][k] 32 KB, swizzled

  // ---- stage: t -> (m = t>>5, layer sj = (t>>3)&3, k-chunk sh = t&7) ----
  // 128B contiguous per thread; a wave covers 8KB contiguous of x.
  const int sm = t >> 5, sj = (t >> 3) & 3, sh = t & 7;
  const float* xsrc = X + ((size_t)(mbase + sm) * NL + n0 + sj) * DK + sh * 32;
  f32x4 xv[8];
#pragma unroll
  for (int j = 0; j < 8; ++j) xv[j] = *(const f32x4*)(xsrc + j * 4);

  // convert + swizzled write: chunk c = sh*4+q (k = c*8), slot = c ^ (sm&7)
  char* abw = (char*)&Alds[sj][sm][0];
#pragma unroll
  for (int q = 0; q < 4; ++q) {
    u16x8 w;
    const f32x4 a0 = xv[2 * q], a1 = xv[2 * q + 1];
#pragma unroll
    for (int e = 0; e < 4; ++e) { w[e] = f2bf(a0[e]); w[4 + e] = f2bf(a1[e]); }
    *(u16x8*)(abw + (((sh * 4 + q) ^ (sm & 7)) << 4)) = w;
  }
  __syncthreads();  // the only barrier

  // ---- compute: wave -> (layer j = wave>>1, o-half = wave&1) ----
  const int j    = wave >> 1;
  const int half = wave & 1;
  const int n    = n0 + j;
  const unsigned short* Wn = Wt + (size_t)n * DO_ * DK;
  const char* aj = (const char*)&Alds[j][0][0];

  f32x4 acc[8];
#pragma unroll
  for (int oj = 0; oj < 8; ++oj) acc[oj] = (f32x4){0.f, 0.f, 0.f, 0.f};

  // B-load: coalesced 1KB per instr from prefragmented, L2-resident Wt
#define BLOAD(s, oj) \
  (*(const bf16x8*)(Wn + ((size_t)((half * 8 + (oj)) * 8 + (s)) * 64 + lane) * 8))
  // A-fragment: verified swizzled read
#define ALOAD(s) \
  (*(const bf16x8*)(aj + lrow * 512 + ((((s) * 4 + lhi) ^ (lrow & 7)) << 4)))

  bf16x8 bA[8], bB[8], afA, afB;
#pragma unroll
  for (int oj = 0; oj < 8; ++oj) bA[oj] = BLOAD(0, oj);
  afA = ALOAD(0);

#pragma unroll
  for (int s = 0; s < 8; ++s) {
    const bool odd = (s & 1) != 0;
    if (s < 7) {  // 1-step static lookahead (fills the other register set)
      if (!odd) {
#pragma unroll
        for (int oj = 0; oj < 8; ++oj) bB[oj] = BLOAD(s + 1, oj);
        afB = ALOAD(s + 1);
      } else {
#pragma unroll
        for (int oj = 0; oj < 8; ++oj) bA[oj] = BLOAD(s + 1, oj);
        afA = ALOAD(s + 1);
      }
    }
    const bf16x8 af = odd ? afB : afA;
#pragma unroll
    for (int oj = 0; oj < 8; ++oj) {  // SWAPPED: D[o][m], lane regs = 4 contig o
      const bf16x8 bf = odd ? bB[oj] : bA[oj];
      acc[oj] = __builtin_amdgcn_mfma_f32_16x16x32_bf16(bf, af, acc[oj], 0, 0, 0);
    }
  }
#undef BLOAD
#undef ALOAD

  // epilogue: m = mbase+lrow, o = half*128 + oj*16 + lhi*4 + r; 4KB/row dense
  const float* bb = bias + n * DO_ + half * 128 + lhi * 4;
  const int m = mbase + lrow;
  float* orow = out + ((size_t)m * NL + n) * DO_ + half * 128 + lhi * 4;
#pragma unroll
  for (int oj = 0; oj < 8; ++oj) {
    const f32x4 bv = *(const f32x4*)(bb + oj * 16);
    *(f32x4*)(orow + oj * 16) = acc[oj] + bv;
  }
}

// ---------------------------------------------------------------------------
// Fallback (only if ws too small for Wt): plain fp32, correct but slow.
// ---------------------------------------------------------------------------
__global__ __launch_bounds__(256) void nlinear_naive(
    const float* __restrict__ X, const float* __restrict__ W,
    const float* __restrict__ B, float* __restrict__ out) {
  const int n = blockIdx.y;
  const int m = blockIdx.x;
  const int o = threadIdx.x;
  __shared__ float xs[DK];
  xs[o] = X[((size_t)m * NL + n) * DK + o];
  __syncthreads();
  const float* Wn = W + (size_t)n * DK * DO_;
  float s = B[n * DO_ + o];
  for (int k = 0; k < DK; ++k) s = fmaf(xs[k], Wn[(size_t)k * DO_ + o], s);
  out[((size_t)m * NL + n) * DO_ + o] = s;
}

extern "C" void kernel_launch(void* const* d_in, const int* in_sizes, int n_in,
                              void* d_out, int out_size, void* d_ws, size_t ws_size,
                              hipStream_t stream) {
  const float* x = (const float*)d_in[0];
  const float* w = (const float*)d_in[1];
  const float* b = (const float*)d_in[2];
  float* out     = (float*)d_out;
  const size_t wt_bytes = (size_t)NL * DK * DO_ * sizeof(unsigned short);
  if (ws_size >= wt_bytes) {
    unsigned short* wt = (unsigned short*)d_ws;
    wt_prep<<<dim3(16, NL), 256, 0, stream>>>(w, wt);
    nlinear_mfma<<<dim3(2048), 512, 0, stream>>>(x, wt, b, out);
  } else {
    nlinear_naive<<<dim3(MB, NL), 256, 0, stream>>>(x, w, b, out);
  }
}